// Round 12
// baseline (1807.622 us; speedup 1.0000x reference)
//
#include <hip/hip_runtime.h>
#include <cmath>

#define TOTAL_RAYS (131072 * 16)
#define HDIM 64

typedef float v2f __attribute__((ext_vector_type(2)));
typedef float v4f __attribute__((ext_vector_type(4)));

__device__ unsigned int g_counter;

__global__ void vis_init_counter() { g_counter = 0u; }

// softplus(x) = max(x,0) + log1p(exp(-|x|)).
// Fast form: v_exp_f32 / v_log_f32 (~2-4 ulp absolute). Verified absmax 0 since round 4.
__device__ __forceinline__ float softplus_f(float x) {
    return fmaxf(x, 0.0f) + __logf(1.0f + __expf(-fabsf(x)));
}

// Weights read via wave-uniform s_load (scalar cache broadcast) — round 11
// took 1088 ds_read_b128/eval off the LDS pipe: VALUBusy 33.6->57.3%,
// VGPR 128->48, LDS 0. This round: grid 1024->2048 blocks. With VGPR=48 and
// no LDS the HW allows 8 waves/SIMD; the old grid capped residency at
// 4 waves/SIMD (4096 waves / 1024 SIMDs). 2048 blocks = 8192 waves = full
// 8/SIMD to hide SMEM + transcendental latency.
extern "C" __global__ void __launch_bounds__(256, 2)
vis_trace_kernel(const float* __restrict__ points,
                 const float* __restrict__ cams,
                 const float* __restrict__ W1,
                 const float* __restrict__ b1,
                 const float* __restrict__ W2,
                 const float* __restrict__ b2,
                 const float* __restrict__ W3,
                 const float* __restrict__ b3,
                 int* __restrict__ out)
{
    const v4f* __restrict__ W2v = reinterpret_cast<const v4f*>(W2);  // row k = W2v[k*16 .. k*16+15]
    const float sB3 = b3[0];                                          // uniform -> SGPR, hoisted

    const int lane = threadIdx.x & 63;

    bool live = false, maskv = false, mint = false, drained = false;
    float ox = 0.f, oy = 0.f, oz = 0.f, dx = 0.f, dy = 0.f, dz = 0.f;
    float farv = 0.f, dist = 0.f, cur = 0.f, t = 1e-3f;
    int it = 0;
    unsigned int ridx = 0u;

    for (;;) {
        // ---- refill dead lanes from the global ray queue ----
        unsigned long long needm = __ballot(!live);
        if (needm != 0ull && !drained) {
            int cnt = __popcll(needm);
            unsigned int base = 0u;
            if (lane == 0) base = atomicAdd(&g_counter, (unsigned int)cnt);
            base = (unsigned int)__shfl((int)base, 0);
            if (base >= TOTAL_RAYS) drained = true;
            if (!live) {
                unsigned int idx = base + (unsigned int)__popcll(needm & ((1ull << lane) - 1ull));
                if (idx < TOTAL_RAYS) {
                    ridx = idx;
                    const int n = (int)(idx >> 4), c = (int)(idx & 15u);
                    ox = points[3 * n]; oy = points[3 * n + 1]; oz = points[3 * n + 2];
                    const float cx = cams[3 * c], cy = cams[3 * c + 1], cz = cams[3 * c + 2];
                    {
                        #pragma clang fp contract(off)
                        float rx = cx - ox, ry = cy - oy, rz = cz - oz;
                        float nrm = sqrtf(rx * rx + ry * ry + rz * rz);
                        dx = rx / nrm; dy = ry / nrm; dz = rz / nrm;
                        float bq = dx * ox + dy * oy + dz * oz;
                        float oo = ox * ox + oy * oy + oz * oz;
                        float disc = bq * bq - (oo - 1.0f);
                        mint = disc > 0.0f;
                        farv = -bq + sqrtf(fmaxf(disc, 0.0f));
                    }
                    live = true; maskv = true; it = 0;
                    dist = 0.f; cur = 0.f; t = 1e-3f;
                }
            }
        }
        if (__ballot(live) == 0ull) break;

        // ---- one MLP eval at position t (all lanes; !live lanes compute garbage) ----
        float px, py, pz;
        {
            #pragma clang fp contract(off)
            px = ox + t * dx; py = oy + t * dy; pz = oz + t * dz;
        }

        v2f acc[32];
        #pragma unroll
        for (int q = 0; q < 32; ++q) { v2f z = {0.f, 0.f}; acc[q] = z; }

        #pragma unroll 2
        for (int k = 0; k < HDIM; ++k) {
            // W1 columns + b1: uniform scalar loads (adjacent k merge into s_load_dwordx2)
            float a = fmaf(pz, W1[2 * HDIM + k],
                      fmaf(py, W1[HDIM + k],
                           px * W1[k])) + b1[k];
            float hk = softplus_f(a);
            v2f hk2 = {hk, hk};
            const v4f* row = &W2v[k * 16];
            #pragma unroll
            for (int q = 0; q < 16; ++q) {
                v4f w = row[q];                               // uniform addr -> s_load, SGPR broadcast
                v2f w0 = __builtin_shufflevector(w, w, 0, 1);
                v2f w1 = __builtin_shufflevector(w, w, 2, 3);
                acc[2 * q]     = __builtin_elementwise_fma(hk2, w0, acc[2 * q]);     // v_pk_fma_f32
                acc[2 * q + 1] = __builtin_elementwise_fma(hk2, w1, acc[2 * q + 1]);
            }
        }

        float s3 = 0.f;
        #pragma unroll
        for (int q = 0; q < 32; ++q) {
            float h2 = softplus_f(acc[q].x + b2[2 * q]);
            s3 = fmaf(h2, W3[2 * q], s3);
            float h3 = softplus_f(acc[q].y + b2[2 * q + 1]);
            s3 = fmaf(h3, W3[2 * q + 1], s3);
        }
        const float s = s3 + sB3;

        // ---- state update (reference semantics, incl. it==0 init step) ----
        if (live) {
            if (it == 0) {
                cur = s; maskv = (cur >= 0.0f); dist = 1e-3f + cur;
            } else {
                cur = maskv ? s : cur;
                maskv = maskv && (cur >= 5e-7f);
                dist = maskv ? (dist + cur) : dist;
                maskv = maskv && (dist <= farv);
            }
            ++it; t = dist;
            if (!maskv || it >= 32) {       // frozen or all 32 evals done
                out[ridx] = ((dist > farv) && mint) ? 1 : 0;
                live = false;
            }
        }
    }
}

extern "C" void kernel_launch(void* const* d_in, const int* in_sizes, int n_in,
                              void* d_out, int out_size, void* d_ws, size_t ws_size,
                              hipStream_t stream) {
    const float* points = (const float*)d_in[0];
    const float* cams   = (const float*)d_in[1];
    const float* W1     = (const float*)d_in[2];
    const float* b1     = (const float*)d_in[3];
    const float* W2     = (const float*)d_in[4];
    const float* b2     = (const float*)d_in[5];
    const float* W3     = (const float*)d_in[6];
    const float* b3     = (const float*)d_in[7];
    int* out = (int*)d_out;

    hipLaunchKernelGGL(vis_init_counter, dim3(1), dim3(1), 0, stream);
    hipLaunchKernelGGL(vis_trace_kernel, dim3(2048), dim3(256), 0, stream,
                       points, cams, W1, b1, W2, b2, W3, b3, out);
}

// Round 13
// 1399.620 us; speedup vs baseline: 1.2915x; 1.2915x over previous
//
#include <hip/hip_runtime.h>
#include <cmath>

#define TOTAL_RAYS (131072 * 16)
#define HDIM 64
#define NSHARD 32
#define SHARD_SZ (TOTAL_RAYS / NSHARD)   // 65536

typedef float v2f __attribute__((ext_vector_type(2)));
typedef float v4f __attribute__((ext_vector_type(4)));

// 32 queue counters, each on its own 64B line to kill same-line atomic serialization
__device__ unsigned int g_counters[NSHARD * 16];

__global__ void vis_init_counter() { g_counters[threadIdx.x * 16] = 0u; }

// softplus(x) = max(x,0) + log1p(exp(-|x|)).
// Fast form: v_exp_f32 / v_log_f32 (~2-4 ulp absolute). Verified absmax 0 since round 4.
__device__ __forceinline__ float softplus_f(float x) {
    return fmaxf(x, 0.0f) + __logf(1.0f + __expf(-fabsf(x)));
}

// Weights via wave-uniform s_load (scalar-cache broadcast; round 11: VALUBusy 33.6->57%).
// Round 13: 32-way sharded ray queue — round 12 showed a serialized shared resource
// (more waves, same dur, VALUBusy flat 57%); ~350K atomicAdds on ONE cache line at
// ~6cy each ~= 0.9ms serialized. Sharding cuts per-line rate 32x.
extern "C" __global__ void __launch_bounds__(256, 2)
vis_trace_kernel(const float* __restrict__ points,
                 const float* __restrict__ cams,
                 const float* __restrict__ W1,
                 const float* __restrict__ b1,
                 const float* __restrict__ W2,
                 const float* __restrict__ b2,
                 const float* __restrict__ W3,
                 const float* __restrict__ b3,
                 int* __restrict__ out)
{
    const v4f* __restrict__ W2v = reinterpret_cast<const v4f*>(W2);  // row k = W2v[k*16 .. k*16+15]
    const float sB3 = b3[0];                                          // uniform -> SGPR, hoisted

    const int lane = threadIdx.x & 63;
    int cursh = (int)((blockIdx.x * 4u + (threadIdx.x >> 6)) & (NSHARD - 1));
    int drained_cnt = 0;

    bool live = false, maskv = false, mint = false, drained = false;
    float ox = 0.f, oy = 0.f, oz = 0.f, dx = 0.f, dy = 0.f, dz = 0.f;
    float farv = 0.f, dist = 0.f, cur = 0.f, t = 1e-3f;
    int it = 0;
    unsigned int ridx = 0u;

    for (;;) {
        // ---- refill dead lanes from this wave's current queue shard ----
        unsigned long long needm = __ballot(!live);
        if (needm != 0ull && !drained) {
            int cnt = __popcll(needm);
            unsigned int base = 0u;
            if (lane == 0) base = atomicAdd(&g_counters[cursh * 16], (unsigned int)cnt);
            base = (unsigned int)__shfl((int)base, 0);
            if (base >= (unsigned int)SHARD_SZ) {
                cursh = (cursh + 1) & (NSHARD - 1);      // shard empty -> rotate
                if (++drained_cnt >= NSHARD) drained = true;  // saw all shards empty
            } else {
                drained_cnt = 0;
                if (!live) {
                    unsigned int off = base + (unsigned int)__popcll(needm & ((1ull << lane) - 1ull));
                    if (off < (unsigned int)SHARD_SZ) {
                        unsigned int idx = (unsigned int)cursh * SHARD_SZ + off;
                        ridx = idx;
                        const int n = (int)(idx >> 4), c = (int)(idx & 15u);
                        ox = points[3 * n]; oy = points[3 * n + 1]; oz = points[3 * n + 2];
                        const float cx = cams[3 * c], cy = cams[3 * c + 1], cz = cams[3 * c + 2];
                        {
                            #pragma clang fp contract(off)
                            float rx = cx - ox, ry = cy - oy, rz = cz - oz;
                            float nrm = sqrtf(rx * rx + ry * ry + rz * rz);
                            dx = rx / nrm; dy = ry / nrm; dz = rz / nrm;
                            float bq = dx * ox + dy * oy + dz * oz;
                            float oo = ox * ox + oy * oy + oz * oz;
                            float disc = bq * bq - (oo - 1.0f);
                            mint = disc > 0.0f;
                            farv = -bq + sqrtf(fmaxf(disc, 0.0f));
                        }
                        live = true; maskv = true; it = 0;
                        dist = 0.f; cur = 0.f; t = 1e-3f;
                    }
                }
            }
        }
        if (__ballot(live) == 0ull) {
            if (drained) break;
            continue;                                    // shards left -> retry refill
        }

        // ---- one MLP eval at position t (all lanes; !live lanes compute garbage) ----
        float px, py, pz;
        {
            #pragma clang fp contract(off)
            px = ox + t * dx; py = oy + t * dy; pz = oz + t * dz;
        }

        v2f acc[32];
        #pragma unroll
        for (int q = 0; q < 32; ++q) { v2f z = {0.f, 0.f}; acc[q] = z; }

        #pragma unroll 2
        for (int k = 0; k < HDIM; ++k) {
            // W1 columns + b1: uniform scalar loads (adjacent k merge into s_load_dwordx2)
            float a = fmaf(pz, W1[2 * HDIM + k],
                      fmaf(py, W1[HDIM + k],
                           px * W1[k])) + b1[k];
            float hk = softplus_f(a);
            v2f hk2 = {hk, hk};
            const v4f* row = &W2v[k * 16];
            #pragma unroll
            for (int q = 0; q < 16; ++q) {
                v4f w = row[q];                               // uniform addr -> s_load, SGPR broadcast
                v2f w0 = __builtin_shufflevector(w, w, 0, 1);
                v2f w1 = __builtin_shufflevector(w, w, 2, 3);
                acc[2 * q]     = __builtin_elementwise_fma(hk2, w0, acc[2 * q]);     // v_pk_fma_f32
                acc[2 * q + 1] = __builtin_elementwise_fma(hk2, w1, acc[2 * q + 1]);
            }
        }

        float s3 = 0.f;
        #pragma unroll
        for (int q = 0; q < 32; ++q) {
            float h2 = softplus_f(acc[q].x + b2[2 * q]);
            s3 = fmaf(h2, W3[2 * q], s3);
            float h3 = softplus_f(acc[q].y + b2[2 * q + 1]);
            s3 = fmaf(h3, W3[2 * q + 1], s3);
        }
        const float s = s3 + sB3;

        // ---- state update (reference semantics, incl. it==0 init step) ----
        if (live) {
            if (it == 0) {
                cur = s; maskv = (cur >= 0.0f); dist = 1e-3f + cur;
            } else {
                cur = maskv ? s : cur;
                maskv = maskv && (cur >= 5e-7f);
                dist = maskv ? (dist + cur) : dist;
                maskv = maskv && (dist <= farv);
            }
            ++it; t = dist;
            if (!maskv || it >= 32) {       // frozen or all 32 evals done
                out[ridx] = ((dist > farv) && mint) ? 1 : 0;
                live = false;
            }
        }
    }
}

extern "C" void kernel_launch(void* const* d_in, const int* in_sizes, int n_in,
                              void* d_out, int out_size, void* d_ws, size_t ws_size,
                              hipStream_t stream) {
    const float* points = (const float*)d_in[0];
    const float* cams   = (const float*)d_in[1];
    const float* W1     = (const float*)d_in[2];
    const float* b1     = (const float*)d_in[3];
    const float* W2     = (const float*)d_in[4];
    const float* b2     = (const float*)d_in[5];
    const float* W3     = (const float*)d_in[6];
    const float* b3     = (const float*)d_in[7];
    int* out = (int*)d_out;

    hipLaunchKernelGGL(vis_init_counter, dim3(1), dim3(NSHARD), 0, stream);
    hipLaunchKernelGGL(vis_trace_kernel, dim3(2048), dim3(256), 0, stream,
                       points, cams, W1, b1, W2, b2, W3, b3, out);
}